// Round 25
// baseline (37.019 us; speedup 1.0000x reference)
//
#include <hip/hip_runtime.h>
#include <hip/hip_bf16.h>
#include <math.h>

#define NH 16
#define SL 2048
#define DM 128

typedef float f32x4 __attribute__((ext_vector_type(4)));
typedef short s16x8 __attribute__((ext_vector_type(8)));
typedef short s16x4 __attribute__((ext_vector_type(4)));
typedef int   i32x4 __attribute__((ext_vector_type(4)));

static __device__ __forceinline__ unsigned short f2bfu(float f) {
  __hip_bfloat16 h = __float2bfloat16(f);
  return (unsigned short)__builtin_bit_cast(short, h);
}
static __device__ __forceinline__ short f2bf(float f) {
  __hip_bfloat16 h = __float2bfloat16(f);
  return __builtin_bit_cast(short, h);
}
static __device__ __forceinline__ unsigned pack2(float lo, float hi) {
  return (unsigned)f2bfu(lo) | ((unsigned)f2bfu(hi) << 16);
}

// R20/R24 winner (28.07us) + EXTENDED setprio scope: priority 1 held through
// the ENTIRE per-tile serial chain (QK -> mask -> softmax -> PV), dropped to 0
// only for the bulk staging (WRITEKV + next LOADT). Rationale: R23 ablation
// proved setprio is worth 24% here (chain wave issues ahead of the 7 other
// resident waves' staging); softmax IS part of the chain but previously ran at
// prio 0, competing round-robin with staging VALU. Also 2 fewer setprio/tile.
// Everything else byte-identical: 4-wave block = 64 q-rows, KV tile 64, K
// row-major bf16 swizzled + V^T swizzled, dbuf (64KB LDS, 2 blocks/CU), reg-
// staged with ONE barrier per tile, swapped QK^T, exp2 softmax, hoisted mask
// ballot, lazy defer-max, tree max/psum, deferred l-reduction, P->PV
// in-register via shuffles, fp32 acc, complementary block pairing.
__global__ __launch_bounds__(256) void attn_dbuf(
    const float* __restrict__ qg,
    const float* __restrict__ kg,
    const float* __restrict__ vg,
    const int* __restrict__ offs, int n_off,
    float* __restrict__ out)
{
  __shared__ __align__(16) char Kb[2][16384];
  __shared__ __align__(16) char Vb[2][16384];

  const int t    = threadIdx.x;
  const int lane = t & 63;
  const int w    = t >> 6;
  const int col  = lane & 15;
  const int g    = lane >> 4;

  // complementary pairing: blocks b (z=0: 8-u tiles) and b+256 (z=1: u+1) pair to 9
  const int blk = blockIdx.x;
  const int z   = blk >> 8;
  const int y   = (blk >> 4) & 15;
  const int h   = blk & 15;
  const int dno = y >> 2, u = y & 3;
  const int p   = z ? u : 7 - u;
  const int q0  = (dno * 8 + p) * 64;

  const float* qh = qg + (size_t)h * SL * DM;
  const float* kh = kg + (size_t)h * SL * DM;
  const float* vh = vg + (size_t)h * SL * DM;

  // 1/sqrt(128) * log2(e): QK^T lands directly in exp2 domain
  const float scale2 = 0.08838834764831843f * 1.4426950408889634f;

  const int qrow = q0 + 16 * w + col;

  // offsets: parallel predicated loads (sorted ascending -> max of o<=pos)
  int ov[8];
  #pragma unroll
  for (int ii = 0; ii < 8; ++ii) ov[ii] = (ii < n_off) ? offs[ii] : 0x7fffffff;
  int qstart = 0, kv_lo = 0;
  #pragma unroll
  for (int ii = 0; ii < 8; ++ii) {
    if (ov[ii] <= qrow) qstart = max(qstart, ov[ii]);
    if (ov[ii] <= q0)   kv_lo  = max(kv_lo, ov[ii]);
  }
  const int n = ((q0 + 64) - kv_lo) >> 6;  // KV tiles for this block

  // one-time ballot: any lane whose doc starts inside this block's KV range?
  const bool qsdiff = __any(qstart != kv_lo);

  // Q fragment, pre-scaled. Lane holds [row=col][k=8g+j] per 32-k group kk.
  s16x8 qf[4];
  #pragma unroll
  for (int kk = 0; kk < 4; ++kk) {
    const float* qp = qh + (size_t)qrow * DM + 32 * kk + 8 * g;
    f32x4 lo = *(const f32x4*)qp;
    f32x4 hi = *(const f32x4*)(qp + 4);
    s16x8 f;
    f[0] = f2bf(lo[0] * scale2); f[1] = f2bf(lo[1] * scale2);
    f[2] = f2bf(lo[2] * scale2); f[3] = f2bf(lo[3] * scale2);
    f[4] = f2bf(hi[0] * scale2); f[5] = f2bf(hi[1] * scale2);
    f[6] = f2bf(hi[2] * scale2); f[7] = f2bf(hi[3] * scale2);
    qf[kk] = f;
  }

  f32x4 acc[8];
  #pragma unroll
  for (int dt = 0; dt < 8; ++dt) { f32x4 zv = {0.f, 0.f, 0.f, 0.f}; acc[dt] = zv; }
  float m_ = -1e30f;
  float l_ = 0.f;                          // per-lane partial (reduced in epilogue)

  // staging: thread covers K rows r0+8i (cols d0..d0+3) and V rows r0*4+32k+j
  const int d0  = (t & 31) * 4;
  const int r0  = t >> 5;
  const int rot = (t >> 1) & 3;
  f32x4 kr[8], vr[8];

#define LOADT(T) do {                                                         \
    const float* _ks = kh + (size_t)(kv_lo + ((T) << 6)) * DM;                \
    const float* _vs = vh + (size_t)(kv_lo + ((T) << 6)) * DM;                \
    _Pragma("unroll")                                                         \
    for (int _i = 0; _i < 8; ++_i)                                            \
      kr[_i] = *(const f32x4*)(_ks + (size_t)(r0 + 8 * _i) * DM + d0);        \
    _Pragma("unroll")                                                         \
    for (int _k = 0; _k < 2; ++_k) {                                          \
      _Pragma("unroll")                                                       \
      for (int _j = 0; _j < 4; ++_j)                                          \
        vr[_k * 4 + _j] =                                                     \
          *(const f32x4*)(_vs + (size_t)(r0 * 4 + 32 * _k + _j) * DM + d0);   \
    }                                                                         \
  } while (0)

#define WRITEKV(B) do {                                                       \
    _Pragma("unroll")                                                         \
    for (int _i = 0; _i < 8; ++_i) {                                          \
      int _r = r0 + 8 * _i;                                                   \
      s16x4 _b;                                                               \
      _b[0] = f2bf(kr[_i][0]); _b[1] = f2bf(kr[_i][1]);                       \
      _b[2] = f2bf(kr[_i][2]); _b[3] = f2bf(kr[_i][3]);                       \
      *(s16x4*)(&Kb[B][0] + ((_r * 256 + d0 * 2) ^ ((_r & 7) << 4))) = _b;    \
    }                                                                         \
    _Pragma("unroll")                                                         \
    for (int _k = 0; _k < 2; ++_k) {                                          \
      int _k0 = r0 * 4 + 32 * _k;                                             \
      _Pragma("unroll")                                                       \
      for (int _di = 0; _di < 4; ++_di) {                                     \
        int _dd = (_di + rot) & 3;                                            \
        int _d  = d0 + _dd;                                                   \
        s16x4 _b;                                                             \
        _b[0] = f2bf(vr[_k * 4 + 0][_dd]); _b[1] = f2bf(vr[_k * 4 + 1][_dd]); \
        _b[2] = f2bf(vr[_k * 4 + 2][_dd]); _b[3] = f2bf(vr[_k * 4 + 3][_dd]); \
        *(s16x4*)(&Vb[B][0] + ((_d * 128 + _k0 * 2) ^ ((_d & 7) << 4))) = _b; \
      }                                                                       \
    }                                                                         \
  } while (0)

  // prologue: stage tile 0 into buffer 0
  LOADT(0);
  WRITEKV(0);
  int cur = 0;

  // P-shuffle source lanes: target (col,g) pulls from col+32*(g&1) and +16
  const int srcA = col + 32 * (g & 1);
  const int srcB = srcA + 16;
  const bool hi2 = (g >> 1) != 0;

  for (int it = 0; it < n; ++it) {
    const int kv0 = kv_lo + (it << 6);
    __syncthreads();                       // release writes, acquire buf[cur]

    const bool pre = (it + 1 < n);
    if (pre) LOADT(it + 1);                // issue next-tile global loads early
    __builtin_amdgcn_sched_barrier(0);     // pin loads before compute

    // ==== elevated priority for the WHOLE serial chain (QK->SM->PV) ====
    __builtin_amdgcn_s_setprio(1);

    // ---- QK^T (swapped): st[kt] = K_tile_kt . Q^T -> S^T[k][q] (exp2 dom) ----
    f32x4 st[4];
    #pragma unroll
    for (int kt = 0; kt < 4; ++kt) { f32x4 zv = {0.f, 0.f, 0.f, 0.f}; st[kt] = zv; }
    #pragma unroll
    for (int kt = 0; kt < 4; ++kt) {
      int row = kt * 16 + col;
      #pragma unroll
      for (int kk = 0; kk < 4; ++kk) {
        s16x8 kf = *(const s16x8*)(&Kb[cur][0] + ((row * 256 + 64 * kk + 16 * g) ^ ((row & 7) << 4)));
        st[kt] = __builtin_amdgcn_mfma_f32_16x16x32_bf16(kf, qf[kk], st[kt], 0, 0, 0);
      }
    }

    // ---- mask: scalar condition (diagonal tile, or conservative qsdiff) ----
    const bool needmask = qsdiff || (it + 1 == n);
    if (needmask) {
      #pragma unroll
      for (int kt = 0; kt < 4; ++kt) {
        #pragma unroll
        for (int r = 0; r < 4; ++r) {
          int kpos = kv0 + kt * 16 + 4 * g + r;
          bool ok = (kpos <= qrow) && (kpos >= qstart);
          st[kt][r] = ok ? st[kt][r] : -3.0e38f;
        }
      }
    }

    // ---- local max: balanced tree (depth 4) ----
    float mk[4];
    #pragma unroll
    for (int kt = 0; kt < 4; ++kt)
      mk[kt] = fmaxf(fmaxf(st[kt][0], st[kt][1]), fmaxf(st[kt][2], st[kt][3]));
    float cm = fmaxf(fmaxf(mk[0], mk[1]), fmaxf(mk[2], mk[3]));

    // lazy defer-max: local-max test; cross-lane reduce only on growth
    float al = 1.f;
    float mn = m_;
    if (!__all(cm <= m_)) {
      cm = fmaxf(cm, __shfl_xor(cm, 16));
      cm = fmaxf(cm, __shfl_xor(cm, 32));
      mn = fmaxf(m_, cm);
      al = __builtin_amdgcn_exp2f(m_ - mn);
      m_ = mn;
      #pragma unroll
      for (int r = 0; r < 4; ++r) {
        float ar = __shfl(al, 4 * g + r);
        #pragma unroll
        for (int dt = 0; dt < 8; ++dt) acc[dt][r] *= ar;
      }
    }

    // ---- exp2 + per-lane partial sum (tree), cross-lane reduce deferred ----
    float ps[4];
    unsigned w01[4], w23[4];
    #pragma unroll
    for (int kt = 0; kt < 4; ++kt) {
      float p0 = __builtin_amdgcn_exp2f(st[kt][0] - mn);
      float p1 = __builtin_amdgcn_exp2f(st[kt][1] - mn);
      float p2 = __builtin_amdgcn_exp2f(st[kt][2] - mn);
      float p3 = __builtin_amdgcn_exp2f(st[kt][3] - mn);
      ps[kt] = (p0 + p1) + (p2 + p3);
      w01[kt] = pack2(p0, p1);
      w23[kt] = pack2(p2, p3);
    }
    l_ = l_ * al + ((ps[0] + ps[1]) + (ps[2] + ps[3]));

    // ---- PV: A-frag assembled in-register via shuffles; acc += P . V ----
    #pragma unroll
    for (int ksel = 0; ksel < 2; ++ksel) {
      unsigned a0 = __shfl(w01[2 * ksel], srcA);
      unsigned a1 = __shfl(w01[2 * ksel + 1], srcA);
      unsigned b0 = __shfl(w23[2 * ksel], srcA);
      unsigned b1 = __shfl(w23[2 * ksel + 1], srcA);
      unsigned c0 = __shfl(w01[2 * ksel], srcB);
      unsigned c1 = __shfl(w01[2 * ksel + 1], srcB);
      unsigned e0 = __shfl(w23[2 * ksel], srcB);
      unsigned e1 = __shfl(w23[2 * ksel + 1], srcB);
      i32x4 uu;
      uu[0] = (int)(hi2 ? a1 : a0);
      uu[1] = (int)(hi2 ? b1 : b0);
      uu[2] = (int)(hi2 ? c1 : c0);
      uu[3] = (int)(hi2 ? e1 : e0);
      s16x8 pa = __builtin_bit_cast(s16x8, uu);
      #pragma unroll
      for (int dt = 0; dt < 8; ++dt) {
        int d = dt * 16 + col;
        s16x8 vf = *(const s16x8*)(&Vb[cur][0] + ((d * 128 + 64 * ksel + 16 * g) ^ ((d & 7) << 4)));
        acc[dt] = __builtin_amdgcn_mfma_f32_16x16x32_bf16(pa, vf, acc[dt], 0, 0, 0);
      }
    }
    __builtin_amdgcn_s_setprio(0);
    // ==== end elevated-priority chain ====

    // ---- convert + write next tile into the other buffer (bulk, prio 0) ----
    if (pre) WRITEKV(cur ^ 1);
    cur ^= 1;
  }
#undef LOADT
#undef WRITEKV

  // ---- epilogue: single cross-lane l reduce, divide, store fp32 ----
  float l0 = l_;
  l0 += __shfl_xor(l0, 16);
  l0 += __shfl_xor(l0, 32);                // row-sum for q-row 'col'
  #pragma unroll
  for (int r = 0; r < 4; ++r) {
    float lr  = __shfl(l0, 4 * g + r);
    float inv = 1.f / lr;
    int row   = q0 + 16 * w + 4 * g + r;
    float* op = out + ((size_t)h * SL + row) * DM + col;
    #pragma unroll
    for (int dt = 0; dt < 8; ++dt) op[dt * 16] = acc[dt][r] * inv;
  }
}

extern "C" void kernel_launch(void* const* d_in, const int* in_sizes, int n_in,
                              void* d_out, int out_size, void* d_ws, size_t ws_size,
                              hipStream_t stream) {
  const float* q = (const float*)d_in[0];
  const float* k = (const float*)d_in[1];
  const float* v = (const float*)d_in[2];
  const int* offs = (const int*)d_in[3];
  const int n_off = in_sizes[3];
  float* out = (float*)d_out;

  const int blocks = NH * (SL / 64); // 512
  attn_dbuf<<<blocks, 256, 0, stream>>>(q, k, v, offs, n_off, out);
}

// Round 27
// 28.166 us; speedup vs baseline: 1.3143x; 1.3143x over previous
//
#include <hip/hip_runtime.h>
#include <hip/hip_bf16.h>
#include <math.h>

#define NH 16
#define SL 2048
#define DM 128

typedef float f32x4 __attribute__((ext_vector_type(4)));
typedef short s16x8 __attribute__((ext_vector_type(8)));
typedef short s16x4 __attribute__((ext_vector_type(4)));
typedef int   i32x4 __attribute__((ext_vector_type(4)));

static __device__ __forceinline__ unsigned short f2bfu(float f) {
  __hip_bfloat16 h = __float2bfloat16(f);
  return (unsigned short)__builtin_bit_cast(short, h);
}
static __device__ __forceinline__ short f2bf(float f) {
  __hip_bfloat16 h = __float2bfloat16(f);
  return __builtin_bit_cast(short, h);
}
static __device__ __forceinline__ unsigned pack2(float lo, float hi) {
  return (unsigned)f2bfu(lo) | ((unsigned)f2bfu(hi) << 16);
}

// R20/R24 winner resubmitted byte-identical (A/A test after R26's post-timing
// divergence — first failure in 10 benches of this structure; race audit of
// the 1-barrier dbuf found no hazard: write-target(it) = read-source(it-1)
// separated by a barrier with lgkmcnt(0) drain; all branch conditions and
// buffer indices block-uniform; blocks independent; out fully overwritten).
// If divergence recurs, next round adds a post-PV barrier.
// Structure: 4-wave block = 64 q-rows, KV tile 64. K row-major bf16 swizzled +
// V^T swizzled, double-buffered (64KB LDS, 2 blocks/CU). Reg-staged: loads for
// t+1 issued before t's compute, converts+ds_writes after, ONE barrier per
// tile. Swapped QK^T -> S^T; exp2-domain softmax; hoisted mask ballot; lazy
// defer-max; tree max/psum; deferred l-reduction; P->PV in-register via
// shuffles; fp32 acc; complementary block pairing (pairs sum to 9 tiles);
// setprio 1 around MFMA clusters only (two-sided ablation optimum).
__global__ __launch_bounds__(256) void attn_dbuf(
    const float* __restrict__ qg,
    const float* __restrict__ kg,
    const float* __restrict__ vg,
    const int* __restrict__ offs, int n_off,
    float* __restrict__ out)
{
  __shared__ __align__(16) char Kb[2][16384];
  __shared__ __align__(16) char Vb[2][16384];

  const int t    = threadIdx.x;
  const int lane = t & 63;
  const int w    = t >> 6;
  const int col  = lane & 15;
  const int g    = lane >> 4;

  // complementary pairing: blocks b (z=0: 8-u tiles) and b+256 (z=1: u+1) pair to 9
  const int blk = blockIdx.x;
  const int z   = blk >> 8;
  const int y   = (blk >> 4) & 15;
  const int h   = blk & 15;
  const int dno = y >> 2, u = y & 3;
  const int p   = z ? u : 7 - u;
  const int q0  = (dno * 8 + p) * 64;

  const float* qh = qg + (size_t)h * SL * DM;
  const float* kh = kg + (size_t)h * SL * DM;
  const float* vh = vg + (size_t)h * SL * DM;

  // 1/sqrt(128) * log2(e): QK^T lands directly in exp2 domain
  const float scale2 = 0.08838834764831843f * 1.4426950408889634f;

  const int qrow = q0 + 16 * w + col;

  // offsets: parallel predicated loads (sorted ascending -> max of o<=pos)
  int ov[8];
  #pragma unroll
  for (int ii = 0; ii < 8; ++ii) ov[ii] = (ii < n_off) ? offs[ii] : 0x7fffffff;
  int qstart = 0, kv_lo = 0;
  #pragma unroll
  for (int ii = 0; ii < 8; ++ii) {
    if (ov[ii] <= qrow) qstart = max(qstart, ov[ii]);
    if (ov[ii] <= q0)   kv_lo  = max(kv_lo, ov[ii]);
  }
  const int n = ((q0 + 64) - kv_lo) >> 6;  // KV tiles for this block

  // one-time ballot: any lane whose doc starts inside this block's KV range?
  const bool qsdiff = __any(qstart != kv_lo);

  // Q fragment, pre-scaled. Lane holds [row=col][k=8g+j] per 32-k group kk.
  s16x8 qf[4];
  #pragma unroll
  for (int kk = 0; kk < 4; ++kk) {
    const float* qp = qh + (size_t)qrow * DM + 32 * kk + 8 * g;
    f32x4 lo = *(const f32x4*)qp;
    f32x4 hi = *(const f32x4*)(qp + 4);
    s16x8 f;
    f[0] = f2bf(lo[0] * scale2); f[1] = f2bf(lo[1] * scale2);
    f[2] = f2bf(lo[2] * scale2); f[3] = f2bf(lo[3] * scale2);
    f[4] = f2bf(hi[0] * scale2); f[5] = f2bf(hi[1] * scale2);
    f[6] = f2bf(hi[2] * scale2); f[7] = f2bf(hi[3] * scale2);
    qf[kk] = f;
  }

  f32x4 acc[8];
  #pragma unroll
  for (int dt = 0; dt < 8; ++dt) { f32x4 zv = {0.f, 0.f, 0.f, 0.f}; acc[dt] = zv; }
  float m_ = -1e30f;
  float l_ = 0.f;                          // per-lane partial (reduced in epilogue)

  // staging: thread covers K rows r0+8i (cols d0..d0+3) and V rows r0*4+32k+j
  const int d0  = (t & 31) * 4;
  const int r0  = t >> 5;
  const int rot = (t >> 1) & 3;
  f32x4 kr[8], vr[8];

#define LOADT(T) do {                                                         \
    const float* _ks = kh + (size_t)(kv_lo + ((T) << 6)) * DM;                \
    const float* _vs = vh + (size_t)(kv_lo + ((T) << 6)) * DM;                \
    _Pragma("unroll")                                                         \
    for (int _i = 0; _i < 8; ++_i)                                            \
      kr[_i] = *(const f32x4*)(_ks + (size_t)(r0 + 8 * _i) * DM + d0);        \
    _Pragma("unroll")                                                         \
    for (int _k = 0; _k < 2; ++_k) {                                          \
      _Pragma("unroll")                                                       \
      for (int _j = 0; _j < 4; ++_j)                                          \
        vr[_k * 4 + _j] =                                                     \
          *(const f32x4*)(_vs + (size_t)(r0 * 4 + 32 * _k + _j) * DM + d0);   \
    }                                                                         \
  } while (0)

#define WRITEKV(B) do {                                                       \
    _Pragma("unroll")                                                         \
    for (int _i = 0; _i < 8; ++_i) {                                          \
      int _r = r0 + 8 * _i;                                                   \
      s16x4 _b;                                                               \
      _b[0] = f2bf(kr[_i][0]); _b[1] = f2bf(kr[_i][1]);                       \
      _b[2] = f2bf(kr[_i][2]); _b[3] = f2bf(kr[_i][3]);                       \
      *(s16x4*)(&Kb[B][0] + ((_r * 256 + d0 * 2) ^ ((_r & 7) << 4))) = _b;    \
    }                                                                         \
    _Pragma("unroll")                                                         \
    for (int _k = 0; _k < 2; ++_k) {                                          \
      int _k0 = r0 * 4 + 32 * _k;                                             \
      _Pragma("unroll")                                                       \
      for (int _di = 0; _di < 4; ++_di) {                                     \
        int _dd = (_di + rot) & 3;                                            \
        int _d  = d0 + _dd;                                                   \
        s16x4 _b;                                                             \
        _b[0] = f2bf(vr[_k * 4 + 0][_dd]); _b[1] = f2bf(vr[_k * 4 + 1][_dd]); \
        _b[2] = f2bf(vr[_k * 4 + 2][_dd]); _b[3] = f2bf(vr[_k * 4 + 3][_dd]); \
        *(s16x4*)(&Vb[B][0] + ((_d * 128 + _k0 * 2) ^ ((_d & 7) << 4))) = _b; \
      }                                                                       \
    }                                                                         \
  } while (0)

  // prologue: stage tile 0 into buffer 0
  LOADT(0);
  WRITEKV(0);
  int cur = 0;

  // P-shuffle source lanes: target (col,g) pulls from col+32*(g&1) and +16
  const int srcA = col + 32 * (g & 1);
  const int srcB = srcA + 16;
  const bool hi2 = (g >> 1) != 0;

  for (int it = 0; it < n; ++it) {
    const int kv0 = kv_lo + (it << 6);
    __syncthreads();                       // release writes, acquire buf[cur]

    const bool pre = (it + 1 < n);
    if (pre) LOADT(it + 1);                // issue next-tile global loads early
    __builtin_amdgcn_sched_barrier(0);     // pin loads before compute

    // ---- QK^T (swapped): st[kt] = K_tile_kt . Q^T -> S^T[k][q] (exp2 dom) ----
    f32x4 st[4];
    #pragma unroll
    for (int kt = 0; kt < 4; ++kt) { f32x4 zv = {0.f, 0.f, 0.f, 0.f}; st[kt] = zv; }
    __builtin_amdgcn_s_setprio(1);
    #pragma unroll
    for (int kt = 0; kt < 4; ++kt) {
      int row = kt * 16 + col;
      #pragma unroll
      for (int kk = 0; kk < 4; ++kk) {
        s16x8 kf = *(const s16x8*)(&Kb[cur][0] + ((row * 256 + 64 * kk + 16 * g) ^ ((row & 7) << 4)));
        st[kt] = __builtin_amdgcn_mfma_f32_16x16x32_bf16(kf, qf[kk], st[kt], 0, 0, 0);
      }
    }
    __builtin_amdgcn_s_setprio(0);

    // ---- mask: scalar condition (diagonal tile, or conservative qsdiff) ----
    const bool needmask = qsdiff || (it + 1 == n);
    if (needmask) {
      #pragma unroll
      for (int kt = 0; kt < 4; ++kt) {
        #pragma unroll
        for (int r = 0; r < 4; ++r) {
          int kpos = kv0 + kt * 16 + 4 * g + r;
          bool ok = (kpos <= qrow) && (kpos >= qstart);
          st[kt][r] = ok ? st[kt][r] : -3.0e38f;
        }
      }
    }

    // ---- local max: balanced tree (depth 4) ----
    float mk[4];
    #pragma unroll
    for (int kt = 0; kt < 4; ++kt)
      mk[kt] = fmaxf(fmaxf(st[kt][0], st[kt][1]), fmaxf(st[kt][2], st[kt][3]));
    float cm = fmaxf(fmaxf(mk[0], mk[1]), fmaxf(mk[2], mk[3]));

    // lazy defer-max: local-max test; cross-lane reduce only on growth
    float al = 1.f;
    float mn = m_;
    if (!__all(cm <= m_)) {
      cm = fmaxf(cm, __shfl_xor(cm, 16));
      cm = fmaxf(cm, __shfl_xor(cm, 32));
      mn = fmaxf(m_, cm);
      al = __builtin_amdgcn_exp2f(m_ - mn);
      m_ = mn;
      #pragma unroll
      for (int r = 0; r < 4; ++r) {
        float ar = __shfl(al, 4 * g + r);
        #pragma unroll
        for (int dt = 0; dt < 8; ++dt) acc[dt][r] *= ar;
      }
    }

    // ---- exp2 + per-lane partial sum (tree), cross-lane reduce deferred ----
    float ps[4];
    unsigned w01[4], w23[4];
    #pragma unroll
    for (int kt = 0; kt < 4; ++kt) {
      float p0 = __builtin_amdgcn_exp2f(st[kt][0] - mn);
      float p1 = __builtin_amdgcn_exp2f(st[kt][1] - mn);
      float p2 = __builtin_amdgcn_exp2f(st[kt][2] - mn);
      float p3 = __builtin_amdgcn_exp2f(st[kt][3] - mn);
      ps[kt] = (p0 + p1) + (p2 + p3);
      w01[kt] = pack2(p0, p1);
      w23[kt] = pack2(p2, p3);
    }
    l_ = l_ * al + ((ps[0] + ps[1]) + (ps[2] + ps[3]));

    // ---- PV: A-frag assembled in-register via shuffles; acc += P . V ----
    __builtin_amdgcn_s_setprio(1);
    #pragma unroll
    for (int ksel = 0; ksel < 2; ++ksel) {
      unsigned a0 = __shfl(w01[2 * ksel], srcA);
      unsigned a1 = __shfl(w01[2 * ksel + 1], srcA);
      unsigned b0 = __shfl(w23[2 * ksel], srcA);
      unsigned b1 = __shfl(w23[2 * ksel + 1], srcA);
      unsigned c0 = __shfl(w01[2 * ksel], srcB);
      unsigned c1 = __shfl(w01[2 * ksel + 1], srcB);
      unsigned e0 = __shfl(w23[2 * ksel], srcB);
      unsigned e1 = __shfl(w23[2 * ksel + 1], srcB);
      i32x4 uu;
      uu[0] = (int)(hi2 ? a1 : a0);
      uu[1] = (int)(hi2 ? b1 : b0);
      uu[2] = (int)(hi2 ? c1 : c0);
      uu[3] = (int)(hi2 ? e1 : e0);
      s16x8 pa = __builtin_bit_cast(s16x8, uu);
      #pragma unroll
      for (int dt = 0; dt < 8; ++dt) {
        int d = dt * 16 + col;
        s16x8 vf = *(const s16x8*)(&Vb[cur][0] + ((d * 128 + 64 * ksel + 16 * g) ^ ((d & 7) << 4)));
        acc[dt] = __builtin_amdgcn_mfma_f32_16x16x32_bf16(pa, vf, acc[dt], 0, 0, 0);
      }
    }
    __builtin_amdgcn_s_setprio(0);

    // ---- convert + write next tile into the other buffer ----
    if (pre) WRITEKV(cur ^ 1);
    cur ^= 1;
  }
#undef LOADT
#undef WRITEKV

  // ---- epilogue: single cross-lane l reduce, divide, store fp32 ----
  float l0 = l_;
  l0 += __shfl_xor(l0, 16);
  l0 += __shfl_xor(l0, 32);                // row-sum for q-row 'col'
  #pragma unroll
  for (int r = 0; r < 4; ++r) {
    float lr  = __shfl(l0, 4 * g + r);
    float inv = 1.f / lr;
    int row   = q0 + 16 * w + 4 * g + r;
    float* op = out + ((size_t)h * SL + row) * DM + col;
    #pragma unroll
    for (int dt = 0; dt < 8; ++dt) op[dt * 16] = acc[dt][r] * inv;
  }
}

extern "C" void kernel_launch(void* const* d_in, const int* in_sizes, int n_in,
                              void* d_out, int out_size, void* d_ws, size_t ws_size,
                              hipStream_t stream) {
  const float* q = (const float*)d_in[0];
  const float* k = (const float*)d_in[1];
  const float* v = (const float*)d_in[2];
  const int* offs = (const int*)d_in[3];
  const int n_off = in_sizes[3];
  float* out = (float*)d_out;

  const int blocks = NH * (SL / 64); // 512
  attn_dbuf<<<blocks, 256, 0, stream>>>(q, k, v, offs, n_off, out);
}

// Round 28
// 28.052 us; speedup vs baseline: 1.3197x; 1.0041x over previous
//
#include <hip/hip_runtime.h>
#include <hip/hip_bf16.h>
#include <math.h>

#define NH 16
#define SL 2048
#define DM 128

typedef float f32x4 __attribute__((ext_vector_type(4)));
typedef short s16x8 __attribute__((ext_vector_type(8)));
typedef short s16x4 __attribute__((ext_vector_type(4)));
typedef int   i32x4 __attribute__((ext_vector_type(4)));

static __device__ __forceinline__ unsigned short f2bfu(float f) {
  __hip_bfloat16 h = __float2bfloat16(f);
  return (unsigned short)__builtin_bit_cast(short, h);
}
static __device__ __forceinline__ short f2bf(float f) {
  __hip_bfloat16 h = __float2bfloat16(f);
  return __builtin_bit_cast(short, h);
}
static __device__ __forceinline__ unsigned pack2(float lo, float hi) {
  return (unsigned)f2bfu(lo) | ((unsigned)f2bfu(hi) << 16);
}

// TERMINAL STATE: verified-best kernel (28.07-28.17us across 4 clean runs;
// R26's post-timing divergence was a transient — byte-identical A/A retest
// passed). fp32 baseline 910us -> 28.1us (32x).
// Structure: 4-wave block = 64 q-rows, KV tile 64 (swept: 32->35.8, 64->28.1,
// 128->29.1). K row-major bf16 swizzled + V^T swizzled, double-buffered (64KB
// LDS, 2 blocks/CU). Reg-staged dbuf: loads for t+1 issued before t's compute,
// converts+ds_writes after, ONE barrier per tile. Swapped QK^T -> S^T; exp2-
// domain softmax (Q pre-scaled by scale*log2e); hoisted mask ballot (diagonal-
// only); lazy defer-max (local-max test, cross-lane reduce+rescale only on
// growth); tree max/psum; deferred l-reduction; P->PV in-register via
// shuffles; fp32 acc; complementary block pairing (pairs sum to 9 tiles);
// setprio 1 around MFMA clusters ONLY (two-sided ablation: remove -> 37.1us,
// extend through softmax -> 37.0us; this placement is the optimum).
// Lever ledger (all falsified): occupancy up (R9/R15), split-KV (R10/R11),
// 8-wave blocks (R12/R15/R21), KVB 32/128, MFMA-overlap pipeline (R13),
// pairing policies (R16). Winning class: serial-dependency-chain cuts
// (R14/R18/R19/R20: 29.3->28.1). Constraint: 8-tile dependency chain x
// ~3.1us/tile at 2 blocks/CU — a latency floor (HBM 8% / MFMA 4% / VALU 16%),
// not a resource roofline.
__global__ __launch_bounds__(256) void attn_dbuf(
    const float* __restrict__ qg,
    const float* __restrict__ kg,
    const float* __restrict__ vg,
    const int* __restrict__ offs, int n_off,
    float* __restrict__ out)
{
  __shared__ __align__(16) char Kb[2][16384];
  __shared__ __align__(16) char Vb[2][16384];

  const int t    = threadIdx.x;
  const int lane = t & 63;
  const int w    = t >> 6;
  const int col  = lane & 15;
  const int g    = lane >> 4;

  // complementary pairing: blocks b (z=0: 8-u tiles) and b+256 (z=1: u+1) pair to 9
  const int blk = blockIdx.x;
  const int z   = blk >> 8;
  const int y   = (blk >> 4) & 15;
  const int h   = blk & 15;
  const int dno = y >> 2, u = y & 3;
  const int p   = z ? u : 7 - u;
  const int q0  = (dno * 8 + p) * 64;

  const float* qh = qg + (size_t)h * SL * DM;
  const float* kh = kg + (size_t)h * SL * DM;
  const float* vh = vg + (size_t)h * SL * DM;

  // 1/sqrt(128) * log2(e): QK^T lands directly in exp2 domain
  const float scale2 = 0.08838834764831843f * 1.4426950408889634f;

  const int qrow = q0 + 16 * w + col;

  // offsets: parallel predicated loads (sorted ascending -> max of o<=pos)
  int ov[8];
  #pragma unroll
  for (int ii = 0; ii < 8; ++ii) ov[ii] = (ii < n_off) ? offs[ii] : 0x7fffffff;
  int qstart = 0, kv_lo = 0;
  #pragma unroll
  for (int ii = 0; ii < 8; ++ii) {
    if (ov[ii] <= qrow) qstart = max(qstart, ov[ii]);
    if (ov[ii] <= q0)   kv_lo  = max(kv_lo, ov[ii]);
  }
  const int n = ((q0 + 64) - kv_lo) >> 6;  // KV tiles for this block

  // one-time ballot: any lane whose doc starts inside this block's KV range?
  const bool qsdiff = __any(qstart != kv_lo);

  // Q fragment, pre-scaled. Lane holds [row=col][k=8g+j] per 32-k group kk.
  s16x8 qf[4];
  #pragma unroll
  for (int kk = 0; kk < 4; ++kk) {
    const float* qp = qh + (size_t)qrow * DM + 32 * kk + 8 * g;
    f32x4 lo = *(const f32x4*)qp;
    f32x4 hi = *(const f32x4*)(qp + 4);
    s16x8 f;
    f[0] = f2bf(lo[0] * scale2); f[1] = f2bf(lo[1] * scale2);
    f[2] = f2bf(lo[2] * scale2); f[3] = f2bf(lo[3] * scale2);
    f[4] = f2bf(hi[0] * scale2); f[5] = f2bf(hi[1] * scale2);
    f[6] = f2bf(hi[2] * scale2); f[7] = f2bf(hi[3] * scale2);
    qf[kk] = f;
  }

  f32x4 acc[8];
  #pragma unroll
  for (int dt = 0; dt < 8; ++dt) { f32x4 zv = {0.f, 0.f, 0.f, 0.f}; acc[dt] = zv; }
  float m_ = -1e30f;
  float l_ = 0.f;                          // per-lane partial (reduced in epilogue)

  // staging: thread covers K rows r0+8i (cols d0..d0+3) and V rows r0*4+32k+j
  const int d0  = (t & 31) * 4;
  const int r0  = t >> 5;
  const int rot = (t >> 1) & 3;
  f32x4 kr[8], vr[8];

#define LOADT(T) do {                                                         \
    const float* _ks = kh + (size_t)(kv_lo + ((T) << 6)) * DM;                \
    const float* _vs = vh + (size_t)(kv_lo + ((T) << 6)) * DM;                \
    _Pragma("unroll")                                                         \
    for (int _i = 0; _i < 8; ++_i)                                            \
      kr[_i] = *(const f32x4*)(_ks + (size_t)(r0 + 8 * _i) * DM + d0);        \
    _Pragma("unroll")                                                         \
    for (int _k = 0; _k < 2; ++_k) {                                          \
      _Pragma("unroll")                                                       \
      for (int _j = 0; _j < 4; ++_j)                                          \
        vr[_k * 4 + _j] =                                                     \
          *(const f32x4*)(_vs + (size_t)(r0 * 4 + 32 * _k + _j) * DM + d0);   \
    }                                                                         \
  } while (0)

#define WRITEKV(B) do {                                                       \
    _Pragma("unroll")                                                         \
    for (int _i = 0; _i < 8; ++_i) {                                          \
      int _r = r0 + 8 * _i;                                                   \
      s16x4 _b;                                                               \
      _b[0] = f2bf(kr[_i][0]); _b[1] = f2bf(kr[_i][1]);                       \
      _b[2] = f2bf(kr[_i][2]); _b[3] = f2bf(kr[_i][3]);                       \
      *(s16x4*)(&Kb[B][0] + ((_r * 256 + d0 * 2) ^ ((_r & 7) << 4))) = _b;    \
    }                                                                         \
    _Pragma("unroll")                                                         \
    for (int _k = 0; _k < 2; ++_k) {                                          \
      int _k0 = r0 * 4 + 32 * _k;                                             \
      _Pragma("unroll")                                                       \
      for (int _di = 0; _di < 4; ++_di) {                                     \
        int _dd = (_di + rot) & 3;                                            \
        int _d  = d0 + _dd;                                                   \
        s16x4 _b;                                                             \
        _b[0] = f2bf(vr[_k * 4 + 0][_dd]); _b[1] = f2bf(vr[_k * 4 + 1][_dd]); \
        _b[2] = f2bf(vr[_k * 4 + 2][_dd]); _b[3] = f2bf(vr[_k * 4 + 3][_dd]); \
        *(s16x4*)(&Vb[B][0] + ((_d * 128 + _k0 * 2) ^ ((_d & 7) << 4))) = _b; \
      }                                                                       \
    }                                                                         \
  } while (0)

  // prologue: stage tile 0 into buffer 0
  LOADT(0);
  WRITEKV(0);
  int cur = 0;

  // P-shuffle source lanes: target (col,g) pulls from col+32*(g&1) and +16
  const int srcA = col + 32 * (g & 1);
  const int srcB = srcA + 16;
  const bool hi2 = (g >> 1) != 0;

  for (int it = 0; it < n; ++it) {
    const int kv0 = kv_lo + (it << 6);
    __syncthreads();                       // release writes, acquire buf[cur]

    const bool pre = (it + 1 < n);
    if (pre) LOADT(it + 1);                // issue next-tile global loads early
    __builtin_amdgcn_sched_barrier(0);     // pin loads before compute

    // ---- QK^T (swapped): st[kt] = K_tile_kt . Q^T -> S^T[k][q] (exp2 dom) ----
    f32x4 st[4];
    #pragma unroll
    for (int kt = 0; kt < 4; ++kt) { f32x4 zv = {0.f, 0.f, 0.f, 0.f}; st[kt] = zv; }
    __builtin_amdgcn_s_setprio(1);
    #pragma unroll
    for (int kt = 0; kt < 4; ++kt) {
      int row = kt * 16 + col;
      #pragma unroll
      for (int kk = 0; kk < 4; ++kk) {
        s16x8 kf = *(const s16x8*)(&Kb[cur][0] + ((row * 256 + 64 * kk + 16 * g) ^ ((row & 7) << 4)));
        st[kt] = __builtin_amdgcn_mfma_f32_16x16x32_bf16(kf, qf[kk], st[kt], 0, 0, 0);
      }
    }
    __builtin_amdgcn_s_setprio(0);

    // ---- mask: scalar condition (diagonal tile, or conservative qsdiff) ----
    const bool needmask = qsdiff || (it + 1 == n);
    if (needmask) {
      #pragma unroll
      for (int kt = 0; kt < 4; ++kt) {
        #pragma unroll
        for (int r = 0; r < 4; ++r) {
          int kpos = kv0 + kt * 16 + 4 * g + r;
          bool ok = (kpos <= qrow) && (kpos >= qstart);
          st[kt][r] = ok ? st[kt][r] : -3.0e38f;
        }
      }
    }

    // ---- local max: balanced tree (depth 4) ----
    float mk[4];
    #pragma unroll
    for (int kt = 0; kt < 4; ++kt)
      mk[kt] = fmaxf(fmaxf(st[kt][0], st[kt][1]), fmaxf(st[kt][2], st[kt][3]));
    float cm = fmaxf(fmaxf(mk[0], mk[1]), fmaxf(mk[2], mk[3]));

    // lazy defer-max: local-max test; cross-lane reduce only on growth
    float al = 1.f;
    float mn = m_;
    if (!__all(cm <= m_)) {
      cm = fmaxf(cm, __shfl_xor(cm, 16));
      cm = fmaxf(cm, __shfl_xor(cm, 32));
      mn = fmaxf(m_, cm);
      al = __builtin_amdgcn_exp2f(m_ - mn);
      m_ = mn;
      #pragma unroll
      for (int r = 0; r < 4; ++r) {
        float ar = __shfl(al, 4 * g + r);
        #pragma unroll
        for (int dt = 0; dt < 8; ++dt) acc[dt][r] *= ar;
      }
    }

    // ---- exp2 + per-lane partial sum (tree), cross-lane reduce deferred ----
    float ps[4];
    unsigned w01[4], w23[4];
    #pragma unroll
    for (int kt = 0; kt < 4; ++kt) {
      float p0 = __builtin_amdgcn_exp2f(st[kt][0] - mn);
      float p1 = __builtin_amdgcn_exp2f(st[kt][1] - mn);
      float p2 = __builtin_amdgcn_exp2f(st[kt][2] - mn);
      float p3 = __builtin_amdgcn_exp2f(st[kt][3] - mn);
      ps[kt] = (p0 + p1) + (p2 + p3);
      w01[kt] = pack2(p0, p1);
      w23[kt] = pack2(p2, p3);
    }
    l_ = l_ * al + ((ps[0] + ps[1]) + (ps[2] + ps[3]));

    // ---- PV: A-frag assembled in-register via shuffles; acc += P . V ----
    __builtin_amdgcn_s_setprio(1);
    #pragma unroll
    for (int ksel = 0; ksel < 2; ++ksel) {
      unsigned a0 = __shfl(w01[2 * ksel], srcA);
      unsigned a1 = __shfl(w01[2 * ksel + 1], srcA);
      unsigned b0 = __shfl(w23[2 * ksel], srcA);
      unsigned b1 = __shfl(w23[2 * ksel + 1], srcA);
      unsigned c0 = __shfl(w01[2 * ksel], srcB);
      unsigned c1 = __shfl(w01[2 * ksel + 1], srcB);
      unsigned e0 = __shfl(w23[2 * ksel], srcB);
      unsigned e1 = __shfl(w23[2 * ksel + 1], srcB);
      i32x4 uu;
      uu[0] = (int)(hi2 ? a1 : a0);
      uu[1] = (int)(hi2 ? b1 : b0);
      uu[2] = (int)(hi2 ? c1 : c0);
      uu[3] = (int)(hi2 ? e1 : e0);
      s16x8 pa = __builtin_bit_cast(s16x8, uu);
      #pragma unroll
      for (int dt = 0; dt < 8; ++dt) {
        int d = dt * 16 + col;
        s16x8 vf = *(const s16x8*)(&Vb[cur][0] + ((d * 128 + 64 * ksel + 16 * g) ^ ((d & 7) << 4)));
        acc[dt] = __builtin_amdgcn_mfma_f32_16x16x32_bf16(pa, vf, acc[dt], 0, 0, 0);
      }
    }
    __builtin_amdgcn_s_setprio(0);

    // ---- convert + write next tile into the other buffer ----
    if (pre) WRITEKV(cur ^ 1);
    cur ^= 1;
  }
#undef LOADT
#undef WRITEKV

  // ---- epilogue: single cross-lane l reduce, divide, store fp32 ----
  float l0 = l_;
  l0 += __shfl_xor(l0, 16);
  l0 += __shfl_xor(l0, 32);                // row-sum for q-row 'col'
  #pragma unroll
  for (int r = 0; r < 4; ++r) {
    float lr  = __shfl(l0, 4 * g + r);
    float inv = 1.f / lr;
    int row   = q0 + 16 * w + 4 * g + r;
    float* op = out + ((size_t)h * SL + row) * DM + col;
    #pragma unroll
    for (int dt = 0; dt < 8; ++dt) op[dt * 16] = acc[dt][r] * inv;
  }
}

extern "C" void kernel_launch(void* const* d_in, const int* in_sizes, int n_in,
                              void* d_out, int out_size, void* d_ws, size_t ws_size,
                              hipStream_t stream) {
  const float* q = (const float*)d_in[0];
  const float* k = (const float*)d_in[1];
  const float* v = (const float*)d_in[2];
  const int* offs = (const int*)d_in[3];
  const int n_off = in_sizes[3];
  float* out = (float*)d_out;

  const int blocks = NH * (SL / 64); // 512
  attn_dbuf<<<blocks, 256, 0, stream>>>(q, k, v, offs, n_off, out);
}